// Round 8
// baseline (465.512 us; speedup 1.0000x reference)
//
#include <hip/hip_runtime.h>
#include <hip/hip_bf16.h>

#define BDIM 1024
#define SEQ  2048
#define NB   2
#define NH   16
#define HDIM 64
#define FFDIM 4096
#define MROWS (NB*SEQ)   // 4096 token rows

typedef __attribute__((ext_vector_type(8))) short short8;
typedef __attribute__((ext_vector_type(4))) float f32x4;

static __device__ __forceinline__ unsigned short f2bf(float f) {
  union { float f; unsigned u; } v; v.f = f;
  unsigned r = v.u + 0x7fffu + ((v.u >> 16) & 1u);
  return (unsigned short)(r >> 16);
}

static __device__ __forceinline__ f32x4 splat4(float x) {
  f32x4 v; v[0] = x; v[1] = x; v[2] = x; v[3] = x; return v;
}

#define GLOAD16(gp, lp)                                                        \
  __builtin_amdgcn_global_load_lds(                                            \
      (const __attribute__((address_space(1))) void*)(gp),                     \
      (__attribute__((address_space(3))) void*)(lp), 16, 0, 0)

// ------- fused fp32 [R][C] -> bf16 [C][R] transpose-convert, all 4 weights ----
// 32x32 tiles; float4 in-loads (16B/lane), LDS transpose, ushort4 out-stores.
__global__ void tcvt_all(const float* __restrict__ w0, const float* __restrict__ w1,
                         const float* __restrict__ w2, const float* __restrict__ w3,
                         unsigned short* __restrict__ o0, unsigned short* __restrict__ o1,
                         unsigned short* __restrict__ o2, unsigned short* __restrict__ o3) {
  const int bid = blockIdx.x;
  const float* in; unsigned short* out; int R, C, nbx, rem;
  if (bid < 3072)      { in = w0; out = o0; R = 1024; C = 3072; rem = bid;        nbx = 96;  }
  else if (bid < 4096) { in = w1; out = o1; R = 1024; C = 1024; rem = bid - 3072; nbx = 32;  }
  else if (bid < 8192) { in = w2; out = o2; R = 1024; C = 4096; rem = bid - 4096; nbx = 128; }
  else                 { in = w3; out = o3; R = 4096; C = 1024; rem = bid - 8192; nbx = 32;  }
  const int c0 = (rem % nbx) * 32, r0 = (rem / nbx) * 32;
  __shared__ float tile[32][36];              // pad 36: aligned float4 stores
  const int t = threadIdx.x;
  {
    const int row = t >> 3, col4 = (t & 7) * 4;
    const float4 v = *(const float4*)(in + (size_t)(r0 + row) * C + c0 + col4);
    *(float4*)&tile[row][col4] = v;
  }
  __syncthreads();
  {
    const int c = t & 31, rg = t >> 5;        // out-row c, 4 r's per thread
    ushort4 o;
    o.x = f2bf(tile[rg * 4 + 0][c]);
    o.y = f2bf(tile[rg * 4 + 1][c]);
    o.z = f2bf(tile[rg * 4 + 2][c]);
    o.w = f2bf(tile[rg * 4 + 3][c]);
    *(ushort4*)(out + (size_t)(c0 + c) * R + r0 + rg * 4) = o;
  }
}

// ---------------- bf16 V-section transpose: qkv[b][s][2048+h*64+d] -> vT[b][h][d][s]
// 64s x 32d tiles; ushort8 loads, LDS transpose, ushort8 stores.
__global__ void vtr_kernel(const unsigned short* __restrict__ qkv,
                           unsigned short* __restrict__ vt) {
  __shared__ unsigned short tile[32][72];     // [d][s], pad 72 (b128-aligned rows)
  const int h = blockIdx.z & 15, b = blockIdx.z >> 4;
  const int s0 = blockIdx.y * 64, d0 = blockIdx.x * 32;
  const int t = threadIdx.x;                  // 256 threads
  const unsigned short* src = qkv + (size_t)b * SEQ * 3072 + 2048 + h * HDIM + d0;
  {
    const int s = t & 63, d8 = (t >> 6) * 8;  // lane-contiguous s: 2-way-free LDS writes
    const short8 v = *(const short8*)(src + (size_t)(s0 + s) * 3072 + d8);
#pragma unroll
    for (int j = 0; j < 8; ++j) tile[d8 + j][s] = (unsigned short)v[j];
  }
  __syncthreads();
  {
    const int d = t >> 3, s8 = (t & 7) * 8;
    const short8 v = *(const short8*)&tile[d][s8];
    *(short8*)(vt + (size_t)(b * NH + h) * HDIM * SEQ + (size_t)(d0 + d) * SEQ + s0 + s8) = v;
  }
}

// ---------------- LayerNorm (fp32 in) -> bf16 out, one block per row ----------
__global__ void ln_kernel(const float* __restrict__ x, const float* __restrict__ g,
                          const float* __restrict__ b, unsigned short* __restrict__ out) {
  const int row = blockIdx.x;
  const int tid = threadIdx.x;            // 256 threads, 4 floats each
  const float4 v = ((const float4*)(x + (size_t)row * BDIM))[tid];
  float s  = v.x + v.y + v.z + v.w;
  float ss = v.x * v.x + v.y * v.y + v.z * v.z + v.w * v.w;
#pragma unroll
  for (int off = 32; off; off >>= 1) { s += __shfl_xor(s, off); ss += __shfl_xor(ss, off); }
  __shared__ float red[8];
  const int wave = tid >> 6;
  if ((tid & 63) == 0) { red[wave * 2] = s; red[wave * 2 + 1] = ss; }
  __syncthreads();
  s  = red[0] + red[2] + red[4] + red[6];
  ss = red[1] + red[3] + red[5] + red[7];
  const float mean = s * (1.0f / BDIM);
  const float inv  = rsqrtf(ss * (1.0f / BDIM) - mean * mean + 1e-5f);
  const float4 gg = ((const float4*)g)[tid];
  const float4 bb = ((const float4*)b)[tid];
  ushort4 o;
  o.x = f2bf((v.x - mean) * inv * gg.x + bb.x);
  o.y = f2bf((v.y - mean) * inv * gg.y + bb.y);
  o.z = f2bf((v.z - mean) * inv * gg.z + bb.z);
  o.w = f2bf((v.w - mean) * inv * gg.w + bb.w);
  ((ushort4*)(out + (size_t)row * BDIM))[tid] = o;
}

// ---------------- GEMM 128x128: C = A[M,K] @ Bt[N,K]^T + bias (+epilogue) -----
template <int EPI>
__global__ __launch_bounds__(256, 3)
void gemm_bt(const unsigned short* __restrict__ A, const unsigned short* __restrict__ Bt,
             const float* __restrict__ bias, const float* __restrict__ resid,
             void* __restrict__ outp, int M, int N, int K) {
  __shared__ unsigned short As[128 * 32];   // 8 KB
  __shared__ unsigned short Bs[128 * 32];   // 8 KB
  const int tid = threadIdx.x;
  const int n0 = blockIdx.x * 128, m0 = blockIdx.y * 128;
  const int lane = tid & 63, wave = tid >> 6;
  const int lr = lane & 15, lg = lane >> 4;
  const int wr = (wave >> 1) * 64, wc = (wave & 1) * 64;

  const unsigned short* ga0 = A  + (size_t)(m0 + (tid >> 2)) * K + (tid & 3) * 8;
  const unsigned short* ga1 = ga0 + (size_t)64 * K;
  const unsigned short* gb0 = Bt + (size_t)(n0 + (tid >> 2)) * K + (tid & 3) * 8;
  const unsigned short* gb1 = gb0 + (size_t)64 * K;
  unsigned short* la0 = As + tid * 8;
  unsigned short* la1 = As + (256 + tid) * 8;
  unsigned short* lb0 = Bs + tid * 8;
  unsigned short* lb1 = Bs + (256 + tid) * 8;

  f32x4 acc[4][4];
#pragma unroll
  for (int i = 0; i < 4; i++)
#pragma unroll
    for (int j = 0; j < 4; j++) acc[i][j] = splat4(0.0f);

  for (int k0 = 0; k0 < K; k0 += 32) {
    GLOAD16(ga0 + k0, la0);
    GLOAD16(ga1 + k0, la1);
    GLOAD16(gb0 + k0, lb0);
    GLOAD16(gb1 + k0, lb1);
    __syncthreads();
    short8 af[4], bfr[4];
#pragma unroll
    for (int mi = 0; mi < 4; mi++)
      af[mi] = *(const short8*)(As + (wr + mi * 16 + lr) * 32 + lg * 8);
#pragma unroll
    for (int ni = 0; ni < 4; ni++)
      bfr[ni] = *(const short8*)(Bs + (wc + ni * 16 + lr) * 32 + lg * 8);
#pragma unroll
    for (int mi = 0; mi < 4; mi++)
#pragma unroll
      for (int ni = 0; ni < 4; ni++)
        acc[mi][ni] = __builtin_amdgcn_mfma_f32_16x16x32_bf16(af[mi], bfr[ni], acc[mi][ni], 0, 0, 0);
    __syncthreads();
  }

  float bv[4];
#pragma unroll
  for (int ni = 0; ni < 4; ni++) bv[ni] = bias[n0 + wc + ni * 16 + lr];
#pragma unroll
  for (int mi = 0; mi < 4; mi++) {
#pragma unroll
    for (int ni = 0; ni < 4; ni++) {
      const int row0 = m0 + wr + mi * 16 + lg * 4;
      const int col  = n0 + wc + ni * 16 + lr;
#pragma unroll
      for (int r = 0; r < 4; r++) {
        const float v = acc[mi][ni][r] + bv[ni];
        const size_t idx = (size_t)(row0 + r) * N + col;
        if constexpr (EPI == 0) {
          ((unsigned short*)outp)[idx] = f2bf(v);
        } else if constexpr (EPI == 1) {
          ((float*)outp)[idx] = v + resid[idx];
        } else {
          const float t = 0.5f * v * (1.0f + erff(v * 0.70710678118f));
          ((unsigned short*)outp)[idx] = f2bf(t);
        }
      }
    }
  }
}

// ---------------- GEMM 128x64 (EPI1: fp32 out = acc+bias+resid) ---------------
__global__ __launch_bounds__(256, 3)
void gemm_bt_n64(const unsigned short* __restrict__ A, const unsigned short* __restrict__ Bt,
                 const float* __restrict__ bias, const float* __restrict__ resid,
                 float* __restrict__ outp, int M, int N, int K) {
  __shared__ unsigned short As[128 * 32];   // 8 KB
  __shared__ unsigned short Bs[64 * 32];    // 4 KB
  const int tid = threadIdx.x;
  const int n0 = blockIdx.x * 64, m0 = blockIdx.y * 128;
  const int lane = tid & 63, wave = tid >> 6;
  const int lr = lane & 15, lg = lane >> 4;
  const int wr = wave * 32;

  const unsigned short* ga0 = A  + (size_t)(m0 + (tid >> 2)) * K + (tid & 3) * 8;
  const unsigned short* ga1 = ga0 + (size_t)64 * K;
  const unsigned short* gb0 = Bt + (size_t)(n0 + (tid >> 2)) * K + (tid & 3) * 8;
  unsigned short* la0 = As + tid * 8;
  unsigned short* la1 = As + (256 + tid) * 8;
  unsigned short* lb0 = Bs + tid * 8;

  f32x4 acc[2][4];
#pragma unroll
  for (int i = 0; i < 2; i++)
#pragma unroll
    for (int j = 0; j < 4; j++) acc[i][j] = splat4(0.0f);

  for (int k0 = 0; k0 < K; k0 += 32) {
    GLOAD16(ga0 + k0, la0);
    GLOAD16(ga1 + k0, la1);
    GLOAD16(gb0 + k0, lb0);
    __syncthreads();
    short8 af[2], bfr[4];
#pragma unroll
    for (int mi = 0; mi < 2; mi++)
      af[mi] = *(const short8*)(As + (wr + mi * 16 + lr) * 32 + lg * 8);
#pragma unroll
    for (int ni = 0; ni < 4; ni++)
      bfr[ni] = *(const short8*)(Bs + (ni * 16 + lr) * 32 + lg * 8);
#pragma unroll
    for (int mi = 0; mi < 2; mi++)
#pragma unroll
      for (int ni = 0; ni < 4; ni++)
        acc[mi][ni] = __builtin_amdgcn_mfma_f32_16x16x32_bf16(af[mi], bfr[ni], acc[mi][ni], 0, 0, 0);
    __syncthreads();
  }

  float bv[4];
#pragma unroll
  for (int ni = 0; ni < 4; ni++) bv[ni] = bias[n0 + ni * 16 + lr];
#pragma unroll
  for (int mi = 0; mi < 2; mi++) {
#pragma unroll
    for (int ni = 0; ni < 4; ni++) {
      const int row0 = m0 + wr + mi * 16 + lg * 4;
      const int col  = n0 + ni * 16 + lr;
#pragma unroll
      for (int r = 0; r < 4; r++) {
        const size_t idx = (size_t)(row0 + r) * N + col;
        outp[idx] = acc[mi][ni][r] + bv[ni] + resid[idx];
      }
    }
  }
}

// ---------------- causal flash attention, v4: zero-barrier --------------------
// One wave per block (64 threads), 32 q-rows per wave, KVBLK=64.
// K fragments read directly from qkv (rows contiguous), V fragments directly
// from pre-transposed vT — both L2-resident; no LDS staging, NO barriers.
// Grid (SEQ/32, NH, NB) = 2048 independent waves.
__global__ __launch_bounds__(64, 3)
void attn_kernel(const unsigned short* __restrict__ qkv,
                 const unsigned short* __restrict__ vT,
                 unsigned short* __restrict__ out) {
  __shared__ unsigned short psw[32 * 72];     // P [q][kv], pad 72
  const int lane = threadIdx.x & 63;
  const int lr = lane & 15, lg = lane >> 4;
  const int wq0 = blockIdx.x * 32;
  const int h = blockIdx.y, bb = blockIdx.z;
  const size_t base = (size_t)bb * SEQ * 3072;
  const unsigned short* kb_g = qkv + base + 1024 + h * HDIM;
  const unsigned short* vth = vT + (size_t)(bb * NH + h) * HDIM * SEQ;
  const float SC = 0.125f * 1.44269504089f;   // scale * log2(e)

  // Q fragments: rows wq0+qb*16+lr, k = kc*32+lg*8
  short8 qf[2][2];
#pragma unroll
  for (int qb = 0; qb < 2; ++qb)
#pragma unroll
    for (int kc = 0; kc < 2; ++kc)
      qf[qb][kc] = *(const short8*)(qkv + base +
          (size_t)(wq0 + qb * 16 + lr) * 3072 + h * HDIM + kc * 32 + lg * 8);

  f32x4 oacc[2][4];
#pragma unroll
  for (int qb = 0; qb < 2; ++qb)
#pragma unroll
    for (int n = 0; n < 4; ++n) oacc[qb][n] = splat4(0.0f);
  f32x4 m_i[2] = { splat4(-INFINITY), splat4(-INFINITY) };
  f32x4 l_i[2] = { splat4(0.0f), splat4(0.0f) };

  const int TB = wq0 / 64 + 1;                // kv tiles of 64 for q < wq0+32

  for (int t = 0; t < TB; ++t) {
    const int kk = t * 64;
    // ---- QK^T: S[32 q][64 kv], K fragments straight from global ----
    short8 kf[4][2];
#pragma unroll
    for (int kb = 0; kb < 4; ++kb)
#pragma unroll
      for (int kc = 0; kc < 2; ++kc)
        kf[kb][kc] = *(const short8*)(kb_g + (size_t)(kk + kb * 16 + lr) * 3072 +
                                      kc * 32 + lg * 8);
    f32x4 s[2][4];
#pragma unroll
    for (int qb = 0; qb < 2; ++qb)
#pragma unroll
      for (int kb = 0; kb < 4; ++kb) s[qb][kb] = splat4(0.0f);
    __builtin_amdgcn_s_setprio(1);
#pragma unroll
    for (int qb = 0; qb < 2; ++qb)
#pragma unroll
      for (int kb = 0; kb < 4; ++kb) {
        s[qb][kb] = __builtin_amdgcn_mfma_f32_16x16x32_bf16(qf[qb][0], kf[kb][0], s[qb][kb], 0, 0, 0);
        s[qb][kb] = __builtin_amdgcn_mfma_f32_16x16x32_bf16(qf[qb][1], kf[kb][1], s[qb][kb], 0, 0, 0);
      }
    __builtin_amdgcn_s_setprio(0);

    // ---- scale (log2 domain) + causal mask ----
    const bool nm = (kk + 64 > wq0);
#pragma unroll
    for (int qb = 0; qb < 2; ++qb)
#pragma unroll
      for (int kb = 0; kb < 4; ++kb)
#pragma unroll
        for (int r = 0; r < 4; ++r) {
          float v = s[qb][kb][r] * SC;
          if (nm) {
            const int q = wq0 + qb * 16 + lg * 4 + r;
            if (kk + kb * 16 + lr > q) v = -INFINITY;
          }
          s[qb][kb][r] = v;
        }

    // ---- online softmax (exp2 domain) ----
    f32x4 mx[2];
#pragma unroll
    for (int qb = 0; qb < 2; ++qb)
#pragma unroll
      for (int r = 0; r < 4; ++r)
        mx[qb][r] = fmaxf(fmaxf(s[qb][0][r], s[qb][1][r]),
                          fmaxf(s[qb][2][r], s[qb][3][r]));
#pragma unroll
    for (int msk = 1; msk < 16; msk <<= 1)
#pragma unroll
      for (int qb = 0; qb < 2; ++qb)
#pragma unroll
        for (int r = 0; r < 4; ++r)
          mx[qb][r] = fmaxf(mx[qb][r], __shfl_xor(mx[qb][r], msk));
    f32x4 mnew[2], corr[2];
#pragma unroll
    for (int qb = 0; qb < 2; ++qb)
#pragma unroll
      for (int r = 0; r < 4; ++r) {
        mnew[qb][r] = fmaxf(m_i[qb][r], mx[qb][r]);
        corr[qb][r] = exp2f(m_i[qb][r] - mnew[qb][r]);
      }
#pragma unroll
    for (int qb = 0; qb < 2; ++qb)
#pragma unroll
      for (int kb = 0; kb < 4; ++kb)
#pragma unroll
        for (int r = 0; r < 4; ++r)
          s[qb][kb][r] = exp2f(s[qb][kb][r] - mnew[qb][r]);
    f32x4 ps[2];
#pragma unroll
    for (int qb = 0; qb < 2; ++qb)
#pragma unroll
      for (int r = 0; r < 4; ++r)
        ps[qb][r] = (s[qb][0][r] + s[qb][1][r]) + (s[qb][2][r] + s[qb][3][r]);
#pragma unroll
    for (int msk = 1; msk < 16; msk <<= 1)
#pragma unroll
      for (int qb = 0; qb < 2; ++qb)
#pragma unroll
        for (int r = 0; r < 4; ++r)
          ps[qb][r] += __shfl_xor(ps[qb][r], msk);
#pragma unroll
    for (int qb = 0; qb < 2; ++qb)
#pragma unroll
      for (int r = 0; r < 4; ++r) {
        l_i[qb][r] = l_i[qb][r] * corr[qb][r] + ps[qb][r];
        m_i[qb][r] = mnew[qb][r];
      }
#pragma unroll
    for (int qb = 0; qb < 2; ++qb)
#pragma unroll
      for (int n = 0; n < 4; ++n)
#pragma unroll
        for (int r = 0; r < 4; ++r) oacc[qb][n][r] *= corr[qb][r];

    // ---- P -> LDS (C-layout -> A-layout; in-wave dep, no barrier) ----
#pragma unroll
    for (int qb = 0; qb < 2; ++qb)
#pragma unroll
      for (int kb = 0; kb < 4; ++kb)
#pragma unroll
        for (int r = 0; r < 4; ++r)
          psw[(qb * 16 + lg * 4 + r) * 72 + kb * 16 + lr] = f2bf(s[qb][kb][r]);

    // ---- PV: O += P[32q][64kv] @ V^T, V fragments straight from vT ----
    short8 pf[2][2], vf[4][2];
#pragma unroll
    for (int qb = 0; qb < 2; ++qb)
#pragma unroll
      for (int kc = 0; kc < 2; ++kc)
        pf[qb][kc] = *(const short8*)(psw + (qb * 16 + lr) * 72 + kc * 32 + lg * 8);
#pragma unroll
    for (int n = 0; n < 4; ++n)
#pragma unroll
      for (int kc = 0; kc < 2; ++kc)
        vf[n][kc] = *(const short8*)(vth + (size_t)(n * 16 + lr) * SEQ +
                                     kk + kc * 32 + lg * 8);
    __builtin_amdgcn_s_setprio(1);
#pragma unroll
    for (int qb = 0; qb < 2; ++qb)
#pragma unroll
      for (int n = 0; n < 4; ++n) {
        oacc[qb][n] = __builtin_amdgcn_mfma_f32_16x16x32_bf16(pf[qb][0], vf[n][0], oacc[qb][n], 0, 0, 0);
        oacc[qb][n] = __builtin_amdgcn_mfma_f32_16x16x32_bf16(pf[qb][1], vf[n][1], oacc[qb][n], 0, 0, 0);
      }
    __builtin_amdgcn_s_setprio(0);
  }

  // ---- write O ----
  f32x4 linv[2];
#pragma unroll
  for (int qb = 0; qb < 2; ++qb)
#pragma unroll
    for (int r = 0; r < 4; ++r) linv[qb][r] = 1.0f / l_i[qb][r];
#pragma unroll
  for (int qb = 0; qb < 2; ++qb)
#pragma unroll
    for (int n = 0; n < 4; ++n)
#pragma unroll
      for (int r = 0; r < 4; ++r)
        out[(size_t)(bb * SEQ + wq0 + qb * 16 + lg * 4 + r) * BDIM + h * HDIM + n * 16 + lr]
            = f2bf(oacc[qb][n][r] * linv[qb][r]);
}

// ---------------- launch ------------------------------------------------------
extern "C" void kernel_launch(void* const* d_in, const int* in_sizes, int n_in,
                              void* d_out, int out_size, void* d_ws, size_t ws_size,
                              hipStream_t stream) {
  const float* x      = (const float*)d_in[0];
  const float* ln1_g  = (const float*)d_in[1];
  const float* ln1_b  = (const float*)d_in[2];
  const float* w_qkv  = (const float*)d_in[3];
  const float* b_qkv  = (const float*)d_in[4];
  const float* w_proj = (const float*)d_in[5];
  const float* b_proj = (const float*)d_in[6];
  const float* ln2_g  = (const float*)d_in[7];
  const float* ln2_b  = (const float*)d_in[8];
  const float* w_fc1  = (const float*)d_in[9];
  const float* b_fc1  = (const float*)d_in[10];
  const float* w_fc2  = (const float*)d_in[11];
  const float* b_fc2  = (const float*)d_in[12];
  float* out = (float*)d_out;

  char* ws = (char*)d_ws;
  unsigned short* wqkvT  = (unsigned short*)(ws + 0);         //  6 MB [3072][1024]
  unsigned short* wprojT = (unsigned short*)(ws + 6291456);   //  2 MB [1024][1024]
  unsigned short* wfc1T  = (unsigned short*)(ws + 8388608);   //  8 MB [4096][1024]
  unsigned short* wfc2T  = (unsigned short*)(ws + 16777216);  //  8 MB [1024][4096]
  unsigned short* hbuf   = (unsigned short*)(ws + 25165824);  //  8 MB [4096][1024] / vT [2][16][64][2048]
  float*          x2     = (float*)         (ws + 33554432);  // 16 MB [4096][1024]
  unsigned short* qkvb   = (unsigned short*)(ws + 50331648);  // 24 MB [4096][3072]
  unsigned short* attnb  = (unsigned short*)(ws + 75497472);  //  8 MB [4096][1024]
  unsigned short* fc1b   = (unsigned short*)(ws + 50331648);  // 32 MB [4096][4096] (reuse)

  tcvt_all<<<12288, 256, 0, stream>>>(w_qkv, w_proj, w_fc1, w_fc2,
                                      wqkvT, wprojT, wfc1T, wfc2T);

  ln_kernel<<<MROWS, 256, 0, stream>>>(x, ln1_g, ln1_b, hbuf);
  gemm_bt<0><<<dim3(3072 / 128, MROWS / 128), 256, 0, stream>>>(hbuf, wqkvT, b_qkv, nullptr, qkvb, MROWS, 3072, 1024);
  vtr_kernel<<<dim3(HDIM / 32, SEQ / 64, NB * NH), 256, 0, stream>>>(qkvb, hbuf);
  attn_kernel<<<dim3(SEQ / 32, NH, NB), 64, 0, stream>>>(qkvb, hbuf, attnb);
  gemm_bt_n64<<<dim3(1024 / 64, MROWS / 128), 256, 0, stream>>>(attnb, wprojT, b_proj, x, x2, MROWS, 1024, 1024);

  ln_kernel<<<MROWS, 256, 0, stream>>>(x2, ln2_g, ln2_b, hbuf);
  gemm_bt<2><<<dim3(4096 / 128, MROWS / 128), 256, 0, stream>>>(hbuf, wfc1T, b_fc1, nullptr, fc1b, MROWS, FFDIM, 1024);
  gemm_bt_n64<<<dim3(1024 / 64, MROWS / 128), 256, 0, stream>>>(fc1b, wfc2T, b_fc2, x2, out, MROWS, 1024, FFDIM);
}

// Round 10
// 422.189 us; speedup vs baseline: 1.1026x; 1.1026x over previous
//
#include <hip/hip_runtime.h>
#include <hip/hip_bf16.h>

#define BDIM 1024
#define SEQ  2048
#define NB   2
#define NH   16
#define HDIM 64
#define FFDIM 4096
#define MROWS (NB*SEQ)   // 4096 token rows

typedef __attribute__((ext_vector_type(8))) short short8;
typedef __attribute__((ext_vector_type(4))) float f32x4;

static __device__ __forceinline__ unsigned short f2bf(float f) {
  union { float f; unsigned u; } v; v.f = f;
  unsigned r = v.u + 0x7fffu + ((v.u >> 16) & 1u);
  return (unsigned short)(r >> 16);
}

static __device__ __forceinline__ f32x4 splat4(float x) {
  f32x4 v; v[0] = x; v[1] = x; v[2] = x; v[3] = x; return v;
}

#define GLOAD16(gp, lp)                                                        \
  __builtin_amdgcn_global_load_lds(                                            \
      (const __attribute__((address_space(1))) void*)(gp),                     \
      (__attribute__((address_space(3))) void*)(lp), 16, 0, 0)

// ------- fused fp32 [R][C] -> bf16 [C][R] transpose-convert, all 4 weights ----
__global__ void tcvt_all(const float* __restrict__ w0, const float* __restrict__ w1,
                         const float* __restrict__ w2, const float* __restrict__ w3,
                         unsigned short* __restrict__ o0, unsigned short* __restrict__ o1,
                         unsigned short* __restrict__ o2, unsigned short* __restrict__ o3) {
  const int bid = blockIdx.x;
  const float* in; unsigned short* out; int R, C, nbx, rem;
  if (bid < 3072)      { in = w0; out = o0; R = 1024; C = 3072; rem = bid;        nbx = 96;  }
  else if (bid < 4096) { in = w1; out = o1; R = 1024; C = 1024; rem = bid - 3072; nbx = 32;  }
  else if (bid < 8192) { in = w2; out = o2; R = 1024; C = 4096; rem = bid - 4096; nbx = 128; }
  else                 { in = w3; out = o3; R = 4096; C = 1024; rem = bid - 8192; nbx = 32;  }
  const int c0 = (rem % nbx) * 32, r0 = (rem / nbx) * 32;
  __shared__ float tile[32][36];              // pad 36: aligned float4 stores
  const int t = threadIdx.x;
  {
    const int row = t >> 3, col4 = (t & 7) * 4;
    const float4 v = *(const float4*)(in + (size_t)(r0 + row) * C + c0 + col4);
    *(float4*)&tile[row][col4] = v;
  }
  __syncthreads();
  {
    const int c = t & 31, rg = t >> 5;        // out-row c, 4 r's per thread
    ushort4 o;
    o.x = f2bf(tile[rg * 4 + 0][c]);
    o.y = f2bf(tile[rg * 4 + 1][c]);
    o.z = f2bf(tile[rg * 4 + 2][c]);
    o.w = f2bf(tile[rg * 4 + 3][c]);
    *(ushort4*)(out + (size_t)(c0 + c) * R + r0 + rg * 4) = o;
  }
}

// ---------------- bf16 V-section transpose: qkv[b][s][2048+h*64+d] -> vT[b][h][d][s]
__global__ void vtr_kernel(const unsigned short* __restrict__ qkv,
                           unsigned short* __restrict__ vt) {
  __shared__ unsigned short tile[32][72];     // [d][s], pad 72 (b128-aligned rows)
  const int h = blockIdx.z & 15, b = blockIdx.z >> 4;
  const int s0 = blockIdx.y * 64, d0 = blockIdx.x * 32;
  const int t = threadIdx.x;                  // 256 threads
  const unsigned short* src = qkv + (size_t)b * SEQ * 3072 + 2048 + h * HDIM + d0;
  {
    const int s = t & 63, d8 = (t >> 6) * 8;  // lane-contiguous s: 2-way-free LDS writes
    const short8 v = *(const short8*)(src + (size_t)(s0 + s) * 3072 + d8);
#pragma unroll
    for (int j = 0; j < 8; ++j) tile[d8 + j][s] = (unsigned short)v[j];
  }
  __syncthreads();
  {
    const int d = t >> 3, s8 = (t & 7) * 8;
    const short8 v = *(const short8*)&tile[d][s8];
    *(short8*)(vt + (size_t)(b * NH + h) * HDIM * SEQ + (size_t)(d0 + d) * SEQ + s0 + s8) = v;
  }
}

// ---------------- LayerNorm (fp32 in) -> bf16 out, one block per row ----------
__global__ void ln_kernel(const float* __restrict__ x, const float* __restrict__ g,
                          const float* __restrict__ b, unsigned short* __restrict__ out) {
  const int row = blockIdx.x;
  const int tid = threadIdx.x;            // 256 threads, 4 floats each
  const float4 v = ((const float4*)(x + (size_t)row * BDIM))[tid];
  float s  = v.x + v.y + v.z + v.w;
  float ss = v.x * v.x + v.y * v.y + v.z * v.z + v.w * v.w;
#pragma unroll
  for (int off = 32; off; off >>= 1) { s += __shfl_xor(s, off); ss += __shfl_xor(ss, off); }
  __shared__ float red[8];
  const int wave = tid >> 6;
  if ((tid & 63) == 0) { red[wave * 2] = s; red[wave * 2 + 1] = ss; }
  __syncthreads();
  s  = red[0] + red[2] + red[4] + red[6];
  ss = red[1] + red[3] + red[5] + red[7];
  const float mean = s * (1.0f / BDIM);
  const float inv  = rsqrtf(ss * (1.0f / BDIM) - mean * mean + 1e-5f);
  const float4 gg = ((const float4*)g)[tid];
  const float4 bb = ((const float4*)b)[tid];
  ushort4 o;
  o.x = f2bf((v.x - mean) * inv * gg.x + bb.x);
  o.y = f2bf((v.y - mean) * inv * gg.y + bb.y);
  o.z = f2bf((v.z - mean) * inv * gg.z + bb.z);
  o.w = f2bf((v.w - mean) * inv * gg.w + bb.w);
  ((ushort4*)(out + (size_t)row * BDIM))[tid] = o;
}

// ---------------- GEMM 128x128: C = A[M,K] @ Bt[N,K]^T + bias (+epilogue) -----
template <int EPI>
__global__ __launch_bounds__(256, 3)
void gemm_bt(const unsigned short* __restrict__ A, const unsigned short* __restrict__ Bt,
             const float* __restrict__ bias, const float* __restrict__ resid,
             void* __restrict__ outp, int M, int N, int K) {
  __shared__ unsigned short As[128 * 32];   // 8 KB
  __shared__ unsigned short Bs[128 * 32];   // 8 KB
  const int tid = threadIdx.x;
  const int n0 = blockIdx.x * 128, m0 = blockIdx.y * 128;
  const int lane = tid & 63, wave = tid >> 6;
  const int lr = lane & 15, lg = lane >> 4;
  const int wr = (wave >> 1) * 64, wc = (wave & 1) * 64;

  const unsigned short* ga0 = A  + (size_t)(m0 + (tid >> 2)) * K + (tid & 3) * 8;
  const unsigned short* ga1 = ga0 + (size_t)64 * K;
  const unsigned short* gb0 = Bt + (size_t)(n0 + (tid >> 2)) * K + (tid & 3) * 8;
  const unsigned short* gb1 = gb0 + (size_t)64 * K;
  unsigned short* la0 = As + tid * 8;
  unsigned short* la1 = As + (256 + tid) * 8;
  unsigned short* lb0 = Bs + tid * 8;
  unsigned short* lb1 = Bs + (256 + tid) * 8;

  f32x4 acc[4][4];
#pragma unroll
  for (int i = 0; i < 4; i++)
#pragma unroll
    for (int j = 0; j < 4; j++) acc[i][j] = splat4(0.0f);

  for (int k0 = 0; k0 < K; k0 += 32) {
    GLOAD16(ga0 + k0, la0);
    GLOAD16(ga1 + k0, la1);
    GLOAD16(gb0 + k0, lb0);
    GLOAD16(gb1 + k0, lb1);
    __syncthreads();
    short8 af[4], bfr[4];
#pragma unroll
    for (int mi = 0; mi < 4; mi++)
      af[mi] = *(const short8*)(As + (wr + mi * 16 + lr) * 32 + lg * 8);
#pragma unroll
    for (int ni = 0; ni < 4; ni++)
      bfr[ni] = *(const short8*)(Bs + (wc + ni * 16 + lr) * 32 + lg * 8);
#pragma unroll
    for (int mi = 0; mi < 4; mi++)
#pragma unroll
      for (int ni = 0; ni < 4; ni++)
        acc[mi][ni] = __builtin_amdgcn_mfma_f32_16x16x32_bf16(af[mi], bfr[ni], acc[mi][ni], 0, 0, 0);
    __syncthreads();
  }

  float bv[4];
#pragma unroll
  for (int ni = 0; ni < 4; ni++) bv[ni] = bias[n0 + wc + ni * 16 + lr];
#pragma unroll
  for (int mi = 0; mi < 4; mi++) {
#pragma unroll
    for (int ni = 0; ni < 4; ni++) {
      const int row0 = m0 + wr + mi * 16 + lg * 4;
      const int col  = n0 + wc + ni * 16 + lr;
#pragma unroll
      for (int r = 0; r < 4; r++) {
        const float v = acc[mi][ni][r] + bv[ni];
        const size_t idx = (size_t)(row0 + r) * N + col;
        if constexpr (EPI == 0) {
          ((unsigned short*)outp)[idx] = f2bf(v);
        } else if constexpr (EPI == 1) {
          ((float*)outp)[idx] = v + resid[idx];
        } else {
          const float t = 0.5f * v * (1.0f + erff(v * 0.70710678118f));
          ((unsigned short*)outp)[idx] = f2bf(t);
        }
      }
    }
  }
}

// ---------------- GEMM 128x64 (EPI1: fp32 out = acc+bias+resid) ---------------
__global__ __launch_bounds__(256, 3)
void gemm_bt_n64(const unsigned short* __restrict__ A, const unsigned short* __restrict__ Bt,
                 const float* __restrict__ bias, const float* __restrict__ resid,
                 float* __restrict__ outp, int M, int N, int K) {
  __shared__ unsigned short As[128 * 32];   // 8 KB
  __shared__ unsigned short Bs[64 * 32];    // 4 KB
  const int tid = threadIdx.x;
  const int n0 = blockIdx.x * 64, m0 = blockIdx.y * 128;
  const int lane = tid & 63, wave = tid >> 6;
  const int lr = lane & 15, lg = lane >> 4;
  const int wr = wave * 32;

  const unsigned short* ga0 = A  + (size_t)(m0 + (tid >> 2)) * K + (tid & 3) * 8;
  const unsigned short* ga1 = ga0 + (size_t)64 * K;
  const unsigned short* gb0 = Bt + (size_t)(n0 + (tid >> 2)) * K + (tid & 3) * 8;
  unsigned short* la0 = As + tid * 8;
  unsigned short* la1 = As + (256 + tid) * 8;
  unsigned short* lb0 = Bs + tid * 8;

  f32x4 acc[2][4];
#pragma unroll
  for (int i = 0; i < 2; i++)
#pragma unroll
    for (int j = 0; j < 4; j++) acc[i][j] = splat4(0.0f);

  for (int k0 = 0; k0 < K; k0 += 32) {
    GLOAD16(ga0 + k0, la0);
    GLOAD16(ga1 + k0, la1);
    GLOAD16(gb0 + k0, lb0);
    __syncthreads();
    short8 af[2], bfr[4];
#pragma unroll
    for (int mi = 0; mi < 2; mi++)
      af[mi] = *(const short8*)(As + (wr + mi * 16 + lr) * 32 + lg * 8);
#pragma unroll
    for (int ni = 0; ni < 4; ni++)
      bfr[ni] = *(const short8*)(Bs + (ni * 16 + lr) * 32 + lg * 8);
#pragma unroll
    for (int mi = 0; mi < 2; mi++)
#pragma unroll
      for (int ni = 0; ni < 4; ni++)
        acc[mi][ni] = __builtin_amdgcn_mfma_f32_16x16x32_bf16(af[mi], bfr[ni], acc[mi][ni], 0, 0, 0);
    __syncthreads();
  }

  float bv[4];
#pragma unroll
  for (int ni = 0; ni < 4; ni++) bv[ni] = bias[n0 + ni * 16 + lr];
#pragma unroll
  for (int mi = 0; mi < 2; mi++) {
#pragma unroll
    for (int ni = 0; ni < 4; ni++) {
      const int row0 = m0 + wr + mi * 16 + lg * 4;
      const int col  = n0 + ni * 16 + lr;
#pragma unroll
      for (int r = 0; r < 4; r++) {
        const size_t idx = (size_t)(row0 + r) * N + col;
        outp[idx] = acc[mi][ni][r] + bv[ni] + resid[idx];
      }
    }
  }
}

// ---------------- causal flash attention, v5 ---------------------------------
// Round-4's verified block-shared-staging body (best measured: 120.7us) +
//  (a) causal PAIRING: each block does q-blocks {p, 15-p} sequentially ->
//      uniform 34 kv-tiles per block; grid 256 = 1 block/CU, no tail.
//  (b) XCD clustering: flat id; id&7 = low bits of (b,h) so all 8 blocks of
//      one head land on one XCD -> K/V (512KB/head) L2-resident.
// 4 waves/block, 32 q-rows/wave (128/block), KVBLK=64, swizzled LDS staging.
__global__ __launch_bounds__(256, 2)
void attn_kernel(const unsigned short* __restrict__ qkv,
                 const unsigned short* __restrict__ vT,
                 unsigned short* __restrict__ out) {
  __shared__ unsigned short Ks[64 * 64];      // swizzled [kv][hd], 8 KB
  __shared__ unsigned short Vs[64 * 64];      // swizzled [d][kv], 8 KB
  __shared__ unsigned short Ps[4][32 * 72];   // per-wave P [q][kv], 18 KB
  const int tid = threadIdx.x;
  const int wave = tid >> 6, lane = tid & 63;
  const int lr = lane & 15, lg = lane >> 4;
  // decode: id&7 -> XCD-pinned low bits of bh; p = pair index 0..7
  const int id = blockIdx.x;
  const int bh = (id & 7) | (((id >> 3) & 3) << 3);   // 0..31
  const int p  = id >> 5;                             // 0..7
  const int h = bh & 15, bb = bh >> 4;
  const size_t base = (size_t)bb * SEQ * 3072;
  const unsigned short* vth = vT + (size_t)bh * HDIM * SEQ;
  unsigned short* psw = Ps[wave];
  const int sw = lr & 7;                      // read-side swizzle key
  const float SC = 0.125f * 1.44269504089f;   // scale * log2(e)

  // staging: thread t covers row srow (32-row passes), col-block pre-swizzled
  const int srow = tid >> 3;                  // 0..31
  const int scb  = (tid & 7) ^ (srow & 7);    // source col-block (involution)
  const unsigned short* kg0 = qkv + base + (size_t)srow * 3072 + 1024 + h * HDIM + scb * 8;
  const unsigned short* vg0 = vth + (size_t)srow * SEQ + scb * 8;
  unsigned short* kl0 = Ks + tid * 8;
  unsigned short* kl1 = Ks + 2048 + tid * 8;
  unsigned short* vl0 = Vs + tid * 8;
  unsigned short* vl1 = Vs + 2048 + tid * 8;

#pragma unroll 1
  for (int half = 0; half < 2; ++half) {
    const int qblk = half ? (15 - p) : p;
    const int Q0 = qblk * 128;
    const int wq0 = Q0 + wave * 32;
    const int TB = qblk * 2 + 2;              // uniform across waves

    // Q fragments: [qb][kc], rows wq0+qb*16+lr, k = kc*32+lg*8
    short8 qf[2][2];
#pragma unroll
    for (int qb = 0; qb < 2; ++qb)
#pragma unroll
      for (int kc = 0; kc < 2; ++kc)
        qf[qb][kc] = *(const short8*)(qkv + base +
            (size_t)(wq0 + qb * 16 + lr) * 3072 + h * HDIM + kc * 32 + lg * 8);

    f32x4 oacc[2][4];
#pragma unroll
    for (int qb = 0; qb < 2; ++qb)
#pragma unroll
      for (int n = 0; n < 4; ++n) oacc[qb][n] = splat4(0.0f);
    f32x4 m_i[2] = { splat4(-INFINITY), splat4(-INFINITY) };
    f32x4 l_i[2] = { splat4(0.0f), splat4(0.0f) };

    for (int t = 0; t < TB; ++t) {
      const int kk = t * 64;
      __syncthreads();                        // previous-iter LDS reads done
      GLOAD16(kg0 + (size_t)kk * 3072, kl0);
      GLOAD16(kg0 + (size_t)(kk + 32) * 3072, kl1);
      GLOAD16(vg0 + kk, vl0);
      GLOAD16(vg0 + (size_t)32 * SEQ + kk, vl1);
      __syncthreads();                        // drains vmcnt for all waves

      // ---- QK^T: S[32 q][64 kv] ----
      short8 kf[4][2];
#pragma unroll
      for (int kb = 0; kb < 4; ++kb)
#pragma unroll
        for (int kc = 0; kc < 2; ++kc)
          kf[kb][kc] = *(const short8*)(Ks + (kb * 16 + lr) * 64 +
                                        (((kc * 4 + lg) ^ sw) * 8));
      f32x4 s[2][4];
#pragma unroll
      for (int qb = 0; qb < 2; ++qb)
#pragma unroll
        for (int kb = 0; kb < 4; ++kb) s[qb][kb] = splat4(0.0f);
      __builtin_amdgcn_s_setprio(1);
#pragma unroll
      for (int qb = 0; qb < 2; ++qb)
#pragma unroll
        for (int kb = 0; kb < 4; ++kb) {
          s[qb][kb] = __builtin_amdgcn_mfma_f32_16x16x32_bf16(qf[qb][0], kf[kb][0], s[qb][kb], 0, 0, 0);
          s[qb][kb] = __builtin_amdgcn_mfma_f32_16x16x32_bf16(qf[qb][1], kf[kb][1], s[qb][kb], 0, 0, 0);
        }
      __builtin_amdgcn_s_setprio(0);

      // ---- scale (log2 domain) + causal mask ----
      const bool nm = (kk + 64 > wq0);
#pragma unroll
      for (int qb = 0; qb < 2; ++qb)
#pragma unroll
        for (int kb = 0; kb < 4; ++kb)
#pragma unroll
          for (int r = 0; r < 4; ++r) {
            float v = s[qb][kb][r] * SC;
            if (nm) {
              const int q = wq0 + qb * 16 + lg * 4 + r;
              if (kk + kb * 16 + lr > q) v = -INFINITY;
            }
            s[qb][kb][r] = v;
          }

      // ---- online softmax (exp2 domain) ----
      f32x4 mx[2];
#pragma unroll
      for (int qb = 0; qb < 2; ++qb)
#pragma unroll
        for (int r = 0; r < 4; ++r)
          mx[qb][r] = fmaxf(fmaxf(s[qb][0][r], s[qb][1][r]),
                            fmaxf(s[qb][2][r], s[qb][3][r]));
#pragma unroll
      for (int msk = 1; msk < 16; msk <<= 1)
#pragma unroll
        for (int qb = 0; qb < 2; ++qb)
#pragma unroll
          for (int r = 0; r < 4; ++r)
            mx[qb][r] = fmaxf(mx[qb][r], __shfl_xor(mx[qb][r], msk));
      f32x4 mnew[2], corr[2];
#pragma unroll
      for (int qb = 0; qb < 2; ++qb)
#pragma unroll
        for (int r = 0; r < 4; ++r) {
          mnew[qb][r] = fmaxf(m_i[qb][r], mx[qb][r]);
          corr[qb][r] = exp2f(m_i[qb][r] - mnew[qb][r]);
        }
#pragma unroll
      for (int qb = 0; qb < 2; ++qb)
#pragma unroll
        for (int kb = 0; kb < 4; ++kb)
#pragma unroll
          for (int r = 0; r < 4; ++r)
            s[qb][kb][r] = exp2f(s[qb][kb][r] - mnew[qb][r]);
      f32x4 ps[2];
#pragma unroll
      for (int qb = 0; qb < 2; ++qb)
#pragma unroll
        for (int r = 0; r < 4; ++r)
          ps[qb][r] = (s[qb][0][r] + s[qb][1][r]) + (s[qb][2][r] + s[qb][3][r]);
#pragma unroll
      for (int msk = 1; msk < 16; msk <<= 1)
#pragma unroll
        for (int qb = 0; qb < 2; ++qb)
#pragma unroll
          for (int r = 0; r < 4; ++r)
            ps[qb][r] += __shfl_xor(ps[qb][r], msk);
#pragma unroll
      for (int qb = 0; qb < 2; ++qb)
#pragma unroll
        for (int r = 0; r < 4; ++r) {
          l_i[qb][r] = l_i[qb][r] * corr[qb][r] + ps[qb][r];
          m_i[qb][r] = mnew[qb][r];
        }
#pragma unroll
      for (int qb = 0; qb < 2; ++qb)
#pragma unroll
        for (int n = 0; n < 4; ++n)
#pragma unroll
          for (int r = 0; r < 4; ++r) oacc[qb][n][r] *= corr[qb][r];

      // ---- P -> LDS (C-layout -> A-layout) ----
#pragma unroll
      for (int qb = 0; qb < 2; ++qb)
#pragma unroll
        for (int kb = 0; kb < 4; ++kb)
#pragma unroll
          for (int r = 0; r < 4; ++r)
            psw[(qb * 16 + lg * 4 + r) * 72 + kb * 16 + lr] = f2bf(s[qb][kb][r]);

      // ---- PV: O += P[32q][64kv] @ V^T[64kv][64d] ----
      short8 pf[2][2], vf[4][2];
#pragma unroll
      for (int qb = 0; qb < 2; ++qb)
#pragma unroll
        for (int kc = 0; kc < 2; ++kc)
          pf[qb][kc] = *(const short8*)(psw + (qb * 16 + lr) * 72 + kc * 32 + lg * 8);
#pragma unroll
      for (int n = 0; n < 4; ++n)
#pragma unroll
        for (int kc = 0; kc < 2; ++kc)
          vf[n][kc] = *(const short8*)(Vs + (n * 16 + lr) * 64 +
                                       (((kc * 4 + lg) ^ sw) * 8));
      __builtin_amdgcn_s_setprio(1);
#pragma unroll
      for (int qb = 0; qb < 2; ++qb)
#pragma unroll
        for (int n = 0; n < 4; ++n) {
          oacc[qb][n] = __builtin_amdgcn_mfma_f32_16x16x32_bf16(pf[qb][0], vf[n][0], oacc[qb][n], 0, 0, 0);
          oacc[qb][n] = __builtin_amdgcn_mfma_f32_16x16x32_bf16(pf[qb][1], vf[n][1], oacc[qb][n], 0, 0, 0);
        }
      __builtin_amdgcn_s_setprio(0);
    }

    // ---- write O ----
    f32x4 linv[2];
#pragma unroll
    for (int qb = 0; qb < 2; ++qb)
#pragma unroll
      for (int r = 0; r < 4; ++r) linv[qb][r] = 1.0f / l_i[qb][r];
#pragma unroll
    for (int qb = 0; qb < 2; ++qb)
#pragma unroll
      for (int n = 0; n < 4; ++n)
#pragma unroll
        for (int r = 0; r < 4; ++r)
          out[(size_t)(bb * SEQ + wq0 + qb * 16 + lg * 4 + r) * BDIM + h * HDIM + n * 16 + lr]
              = f2bf(oacc[qb][n][r] * linv[qb][r]);
  }
}

// ---------------- launch ------------------------------------------------------
extern "C" void kernel_launch(void* const* d_in, const int* in_sizes, int n_in,
                              void* d_out, int out_size, void* d_ws, size_t ws_size,
                              hipStream_t stream) {
  const float* x      = (const float*)d_in[0];
  const float* ln1_g  = (const float*)d_in[1];
  const float* ln1_b  = (const float*)d_in[2];
  const float* w_qkv  = (const float*)d_in[3];
  const float* b_qkv  = (const float*)d_in[4];
  const float* w_proj = (const float*)d_in[5];
  const float* b_proj = (const float*)d_in[6];
  const float* ln2_g  = (const float*)d_in[7];
  const float* ln2_b  = (const float*)d_in[8];
  const float* w_fc1  = (const float*)d_in[9];
  const float* b_fc1  = (const float*)d_in[10];
  const float* w_fc2  = (const float*)d_in[11];
  const float* b_fc2  = (const float*)d_in[12];
  float* out = (float*)d_out;

  char* ws = (char*)d_ws;
  unsigned short* wqkvT  = (unsigned short*)(ws + 0);         //  6 MB [3072][1024]
  unsigned short* wprojT = (unsigned short*)(ws + 6291456);   //  2 MB [1024][1024]
  unsigned short* wfc1T  = (unsigned short*)(ws + 8388608);   //  8 MB [4096][1024]
  unsigned short* wfc2T  = (unsigned short*)(ws + 16777216);  //  8 MB [1024][4096]
  unsigned short* hbuf   = (unsigned short*)(ws + 25165824);  //  8 MB [4096][1024] / vT [2][16][64][2048]
  float*          x2     = (float*)         (ws + 33554432);  // 16 MB [4096][1024]
  unsigned short* qkvb   = (unsigned short*)(ws + 50331648);  // 24 MB [4096][3072]
  unsigned short* attnb  = (unsigned short*)(ws + 75497472);  //  8 MB [4096][1024]
  unsigned short* fc1b   = (unsigned short*)(ws + 50331648);  // 32 MB [4096][4096] (reuse)

  tcvt_all<<<12288, 256, 0, stream>>>(w_qkv, w_proj, w_fc1, w_fc2,
                                      wqkvT, wprojT, wfc1T, wfc2T);

  ln_kernel<<<MROWS, 256, 0, stream>>>(x, ln1_g, ln1_b, hbuf);
  gemm_bt<0><<<dim3(3072 / 128, MROWS / 128), 256, 0, stream>>>(hbuf, wqkvT, b_qkv, nullptr, qkvb, MROWS, 3072, 1024);
  vtr_kernel<<<dim3(HDIM / 32, SEQ / 64, NB * NH), 256, 0, stream>>>(qkvb, hbuf);
  attn_kernel<<<256, 256, 0, stream>>>(qkvb, hbuf, attnb);
  gemm_bt_n64<<<dim3(1024 / 64, MROWS / 128), 256, 0, stream>>>(attnb, wprojT, b_proj, x, x2, MROWS, 1024, 1024);

  ln_kernel<<<MROWS, 256, 0, stream>>>(x2, ln2_g, ln2_b, hbuf);
  gemm_bt<2><<<dim3(4096 / 128, MROWS / 128), 256, 0, stream>>>(hbuf, wfc1T, b_fc1, nullptr, fc1b, MROWS, FFDIM, 1024);
  gemm_bt_n64<<<dim3(1024 / 64, MROWS / 128), 256, 0, stream>>>(fc1b, wfc2T, b_fc2, x2, out, MROWS, 1024, FFDIM);
}